// Round 3
// baseline (743.809 us; speedup 1.0000x reference)
//
#include <hip/hip_runtime.h>
#include <hip/hip_bf16.h>
#include <hip/hip_cooperative_groups.h>

namespace cg = cooperative_groups;

#define NN 50000
#define EE 400000
#define NB 196    // ceil(NN/256)
#define COOPB 1024

typedef __bf16 bf16_8 __attribute__((ext_vector_type(8)));
typedef __bf16 bf16_2 __attribute__((ext_vector_type(2)));
typedef float f32x4 __attribute__((ext_vector_type(4)));
typedef float f32x2 __attribute__((ext_vector_type(2)));

// unpack 2 packed bf16 (one dword) -> 2 f32 (exact, 2 bitops)
__device__ inline f32x2 bf2(unsigned u) {
  f32x2 r;
  r.x = __uint_as_float(u << 16);
  r.y = __uint_as_float(u & 0xffff0000u);
  return r;
}

// ---------------------------------------------------------------- prep (fused)
// [0,1563): f2b; [1563,1691): tr0; [1691,1947): tr1; 1947: ve0; 1948: ve1;
// [1949, 1949+1563): degree count (cnt zeroed by memset before launch)
__global__ __launch_bounds__(256) void prep_kernel(
    const float* __restrict__ features, __bf16* __restrict__ fbf,
    const float* __restrict__ W0, const float* __restrict__ Wres0, __bf16* __restrict__ Bt0,
    const float* __restrict__ W1, __bf16* __restrict__ Bt1,
    const float* __restrict__ We0, const float* __restrict__ ae0, float* __restrict__ Ve0,
    const float* __restrict__ We1, const float* __restrict__ ae1, float* __restrict__ Ve1,
    const int* __restrict__ dst, int* __restrict__ cnt) {
  int b = blockIdx.x;
  int t = threadIdx.x;
  if (b < 1563) {                       // fp32 -> bf16, 8 elems/thread
    int i = b * 256 + t;
    if (i < NN * 64 / 8) {
      const float4* p = (const float4*)features + (size_t)i * 2;
      float4 a = p[0], c = p[1];
      bf16_8 v = {(__bf16)a.x, (__bf16)a.y, (__bf16)a.z, (__bf16)a.w,
                  (__bf16)c.x, (__bf16)c.y, (__bf16)c.z, (__bf16)c.w};
      *(bf16_8*)(fbf + (size_t)i * 8) = v;
    }
  } else if (b < 1563 + 128) {          // Bt0 (512x64): W0^T | Wres0^T
    int idx = (b - 1563) * 256 + t;
    int j = idx >> 6, k = idx & 63;
    float v = (j < 256) ? W0[k * 256 + j] : Wres0[k * 256 + (j - 256)];
    Bt0[idx] = (__bf16)v;
  } else if (b < 1563 + 128 + 256) {    // Bt1 (256x256) = W1^T
    int idx = (b - 1563 - 128) * 256 + t;
    int j = idx >> 8, k = idx & 255;
    Bt1[idx] = (__bf16)W1[k * 256 + j];
  } else if (b == 1947) {               // Ve0
    int f = t >> 2, h = t & 3;
    float s = 0.f;
    for (int d = 0; d < 64; ++d) s += We0[f * 256 + h * 64 + d] * ae0[h * 64 + d];
    Ve0[f * 4 + h] = s;
  } else if (b == 1948) {               // Ve1
    int f = t >> 2, h = t & 3;
    float s = 0.f;
    for (int d = 0; d < 64; ++d) s += We1[f * 256 + h * 64 + d] * ae1[h * 64 + d];
    Ve1[f * 4 + h] = s;
  } else {                              // degree count
    int e = (b - 1949) * 256 + t;
    if (e < EE) atomicAdd(&cnt[dst[e]], 1);
  }
}

// ---------------------------------------------------------------- CSR + fill + eek (cooperative)
// Replaces scan1/scan2/scan3/fill/eek (5 dispatches -> 1). Phases separated by
// grid.sync(): (1) per-block inclusive scan of cnt; (2) block 0 scans block
// sums (exclusive); (3) off/cur; (4) fill via grid-stride atomics; (5) eek
// grid-stride (independent of 4, no sync between them).
__global__ __launch_bounds__(256) void csr_eek_kernel(
    const int* __restrict__ cnt, int* __restrict__ scanbuf,
    int* __restrict__ blocksum, int* __restrict__ blockoff,
    int* __restrict__ off, int* __restrict__ cur,
    const int* __restrict__ src, const int* __restrict__ dst,
    int* __restrict__ srcc, int* __restrict__ pose,
    const float* __restrict__ ef, const float* __restrict__ Ve0,
    const float* __restrict__ Ve1, float* __restrict__ eeo0,
    float* __restrict__ eeo1) {
  cg::grid_group grid = cg::this_grid();
  __shared__ int s[256];
  __shared__ float V0[256], V1[256];
  int t = threadIdx.x;
  int bid = blockIdx.x;

  // phase 1: per-block inclusive scan of cnt (first NB blocks)
  if (bid < NB) {
    int idx = bid * 256 + t;
    int c = (idx < NN) ? cnt[idx] : 0;
    s[t] = c;
    __syncthreads();
    for (int d = 1; d < 256; d <<= 1) {
      int v = (t >= d) ? s[t - d] : 0;
      __syncthreads();
      s[t] += v;
      __syncthreads();
    }
    if (idx < NN) scanbuf[idx] = s[t];
    if (t == 255) blocksum[bid] = s[255];
  }
  grid.sync();

  // phase 2: block 0 scans block sums (exclusive)
  if (bid == 0) {
    int c = (t < NB) ? blocksum[t] : 0;
    s[t] = c;
    __syncthreads();
    for (int d = 1; d < 256; d <<= 1) {
      int v = (t >= d) ? s[t - d] : 0;
      __syncthreads();
      s[t] += v;
      __syncthreads();
    }
    if (t < NB) blockoff[t] = s[t] - c;
  }
  grid.sync();

  // phase 3: off/cur
  if (bid < NB) {
    int idx = bid * 256 + t;
    if (idx < NN) {
      int o = blockoff[bid] + scanbuf[idx] - cnt[idx];
      off[idx] = o;
      cur[idx] = o;
    }
    if (idx == 0) off[NN] = EE;
  }
  grid.sync();

  // phase 4: fill (grid-stride; CSR slot order within a node is arbitrary)
  for (int e = bid * 256 + t; e < EE; e += COOPB * 256) {
    int p = atomicAdd(&cur[dst[e]], 1);
    srcc[p] = src[e];
    pose[e] = p;
  }

  // phase 5: eek (grid-stride over 64-edge chunks; independent of phase 4)
  V0[t] = Ve0[t];
  V1[t] = Ve1[t];
  __syncthreads();
  int r = t >> 2, sub = t & 3;
  for (int eb = bid; eb < (EE + 63) / 64; eb += COOPB) {
    int e = eb * 64 + r;
    if (e >= EE) continue;
    float a0 = 0, a1 = 0, a2 = 0, a3 = 0;
    float c0 = 0, c1 = 0, c2 = 0, c3 = 0;
    const float* row = ef + (size_t)e * 64 + sub * 16;
#pragma unroll
    for (int i = 0; i < 16; i += 4) {
      float4 v = *(const float4*)(row + i);
      float xs[4] = {v.x, v.y, v.z, v.w};
#pragma unroll
      for (int j = 0; j < 4; ++j) {
        float x = xs[j];
        int idx = (sub * 16 + i + j) * 4;
        a0 += x * V0[idx + 0]; a1 += x * V0[idx + 1];
        a2 += x * V0[idx + 2]; a3 += x * V0[idx + 3];
        c0 += x * V1[idx + 0]; c1 += x * V1[idx + 1];
        c2 += x * V1[idx + 2]; c3 += x * V1[idx + 3];
      }
    }
#pragma unroll
    for (int o = 1; o < 4; o <<= 1) {
      a0 += __shfl_xor(a0, o); a1 += __shfl_xor(a1, o);
      a2 += __shfl_xor(a2, o); a3 += __shfl_xor(a3, o);
      c0 += __shfl_xor(c0, o); c1 += __shfl_xor(c1, o);
      c2 += __shfl_xor(c2, o); c3 += __shfl_xor(c3, o);
    }
    if (sub == 0) {
      float4 u; u.x = a0; u.y = a1; u.z = a2; u.w = a3;
      float4 w; w.x = c0; w.y = c1; w.z = c2; w.w = c3;
      *(float4*)(eeo0 + (size_t)e * 4) = u;
      *(float4*)(eeo1 + (size_t)e * 4) = w;
    }
  }
}

// ---------------------------------------------------------------- MFMA GEMM
// C[M x NC] = A @ B, Bt: NC x K row-major. cols<256 -> ft (bf16) + fused el/er;
// cols>=256 -> base = val + bias[col-256] (layer 0 residual).
#define LDK 40
__global__ __launch_bounds__(256) void gemm_kernel(const __bf16* __restrict__ A,
                                                   const __bf16* __restrict__ Bt,
                                                   __bf16* __restrict__ ft,
                                                   __bf16* __restrict__ base,
                                                   const float* __restrict__ bias,
                                                   const float* __restrict__ al,
                                                   const float* __restrict__ ar,
                                                   float* __restrict__ el,
                                                   float* __restrict__ er,
                                                   int M, int K) {
  __shared__ __align__(16) __bf16 Al[64 * LDK];
  __shared__ __align__(16) __bf16 Bl[64 * LDK];
  int tid = threadIdx.x;
  int wav = tid >> 6, lane = tid & 63;
  int quad = lane >> 4, l16 = lane & 15;
  int bm = blockIdx.x * 64;
  int bn = blockIdx.y * 64;
  int sr = tid >> 2;
  int sk = (tid & 3) << 3;

  f32x4 acc[4] = {{0, 0, 0, 0}, {0, 0, 0, 0}, {0, 0, 0, 0}, {0, 0, 0, 0}};

  for (int k0 = 0; k0 < K; k0 += 32) {
    uint4 av = {0, 0, 0, 0};
    int arow = bm + sr;
    if (arow < M) av = *(const uint4*)(A + (size_t)arow * K + k0 + sk);
    uint4 bv = *(const uint4*)(Bt + (size_t)(bn + sr) * K + k0 + sk);
    __syncthreads();
    *(uint4*)&Al[sr * LDK + sk] = av;
    *(uint4*)&Bl[sr * LDK + sk] = bv;
    __syncthreads();
    bf16_8 af = *(const bf16_8*)&Al[(wav * 16 + l16) * LDK + quad * 8];
#pragma unroll
    for (int nt = 0; nt < 4; ++nt) {
      bf16_8 bf = *(const bf16_8*)&Bl[(nt * 16 + l16) * LDK + quad * 8];
      acc[nt] = __builtin_amdgcn_mfma_f32_16x16x32_bf16(af, bf, acc[nt], 0, 0, 0);
    }
  }

  int row0 = bm + wav * 16 + quad * 4;

  // fused el/er for head hb = bn/64 (cols < 256 only)
  if (bn < 256) {
    int hb = bn >> 6;
#pragma unroll
    for (int r = 0; r < 4; ++r) {
      float pl = 0.f, pr = 0.f;
#pragma unroll
      for (int nt = 0; nt < 4; ++nt) {
        float v = acc[nt][r];
        int d = nt * 16 + l16;
        pl += v * al[hb * 64 + d];
        pr += v * ar[hb * 64 + d];
      }
#pragma unroll
      for (int o2 = 8; o2 > 0; o2 >>= 1) {
        pl += __shfl_xor(pl, o2);
        pr += __shfl_xor(pr, o2);
      }
      int row = row0 + r;
      if (l16 == 0 && row < M) {
        el[row * 4 + hb] = pl;
        er[row * 4 + hb] = pr;
      }
    }
  }

#pragma unroll
  for (int nt = 0; nt < 4; ++nt) {
    int col = bn + nt * 16 + l16;
#pragma unroll
    for (int r = 0; r < 4; ++r) {
      int row = row0 + r;
      if (row < M) {
        float v = acc[nt][r];
        if (col < 256)
          ft[(size_t)row * 256 + col] = (__bf16)v;
        else
          base[(size_t)row * 256 + (col - 256)] = (__bf16)(v + bias[col - 256]);
      }
    }
  }
}

// ---------------------------------------------------------------- edge weight pass
// Edge-parallel: w[h] = exp(leaky(el[src]+er[dst]+ee[h])), written in CSR order
// via pose[e]. All reads coalesced; el/er gathers hit an 800KB L2-resident table.
__global__ __launch_bounds__(256) void wk_kernel(const int* __restrict__ src,
                                                 const int* __restrict__ dst,
                                                 const int* __restrict__ pose,
                                                 const float* __restrict__ ee,
                                                 const float* __restrict__ el,
                                                 const float* __restrict__ er,
                                                 float* __restrict__ wcsr) {
  int e = blockIdx.x * 256 + threadIdx.x;
  if (e >= EE) return;
  int s = src[e], d = dst[e], p = pose[e];
  float4 z4 = *(const float4*)(ee + (size_t)e * 4);
  float4 e_l = *(const float4*)(el + (size_t)s * 4);
  float4 e_r = *(const float4*)(er + (size_t)d * 4);
  float4 w;
  float z;
  z = e_l.x + e_r.x + z4.x; w.x = __expf(z > 0.f ? z : 0.2f * z);
  z = e_l.y + e_r.y + z4.y; w.y = __expf(z > 0.f ? z : 0.2f * z);
  z = e_l.z + e_r.z + z4.z; w.z = __expf(z > 0.f ? z : 0.2f * z);
  z = e_l.w + e_r.w + z4.w; w.w = __expf(z > 0.f ? z : 0.2f * z);
  *(float4*)(wcsr + (size_t)p * 4) = w;
}

// ---------------------------------------------------------------- agg
// 2 nodes per block (node = wav>>1); 2 waves per node; each wave covers 2 heads
// (head = (wav&1)*2 + lane/32), each lane holds a bf16x2 dim-pair -> packed
// f32x2 FMA. Per-chunk (32 edges): srcc+wcsr chunk load; weights staged
// DUPLICATED into LDS as {w,w} (ds_read_b64 B-operand, zero VALU). Denominator
// accumulated from each lane's own chunk-load wv, reduced once via shfl_xor.
// Gather unrolled x8 for memory-level parallelism (random-line latency-bound).
template <int LAYER>
__global__ __launch_bounds__(256) void agg_kernel(const int* __restrict__ off,
                                                  const int* __restrict__ srcc,
                                                  const float* __restrict__ wcsr,
                                                  const __bf16* __restrict__ ft,
                                                  const __bf16* prev,
                                                  const float* __restrict__ bias,
                                                  __bf16* outb,
                                                  float* __restrict__ outf) {
  __shared__ f32x2 wl2[2][4][32];
  __shared__ f32x2 red2[2][4][32];
  int t = threadIdx.x;
  int wav = t >> 6, lane = t & 63;
  int nh = wav >> 1;            // node half within block
  int hf = lane >> 5;           // half-wave
  int head = ((wav & 1) << 1) + hf;
  int k32 = lane & 31;
  int n = blockIdx.x * 2 + nh;
  int beg = off[n], end = off[n + 1];
  int offb = head * 128 + k32 * 4;  // byte offset within 512B ft row

  const char* ftb = (const char*)ft;
  f32x2 acc0 = {0.f, 0.f}, acc1 = {0.f, 0.f};
  float denp = 0.f;

  for (int c = beg; c < end; c += 32) {
    int rem = end - c;
    if (rem > 32) rem = 32;
    int sv = 0;
    float wv = 0.f;
    if (k32 < rem) {
      sv = srcc[c + k32];
      wv = wcsr[(size_t)(c + k32) * 4 + head];
    }
    denp += wv;
    f32x2 wd = {wv, wv};
    wl2[nh][head][k32] = wd;
    int kk = 0;
    for (; kk + 8 <= rem; kk += 8) {
      int s0 = __builtin_amdgcn_readlane(sv, kk);
      int s1 = __builtin_amdgcn_readlane(sv, kk + 1);
      int s2 = __builtin_amdgcn_readlane(sv, kk + 2);
      int s3 = __builtin_amdgcn_readlane(sv, kk + 3);
      int s4 = __builtin_amdgcn_readlane(sv, kk + 4);
      int s5 = __builtin_amdgcn_readlane(sv, kk + 5);
      int s6 = __builtin_amdgcn_readlane(sv, kk + 6);
      int s7 = __builtin_amdgcn_readlane(sv, kk + 7);
      unsigned u0 = *(const unsigned*)(ftb + (size_t)s0 * 512 + offb);
      unsigned u1 = *(const unsigned*)(ftb + (size_t)s1 * 512 + offb);
      unsigned u2 = *(const unsigned*)(ftb + (size_t)s2 * 512 + offb);
      unsigned u3 = *(const unsigned*)(ftb + (size_t)s3 * 512 + offb);
      unsigned u4 = *(const unsigned*)(ftb + (size_t)s4 * 512 + offb);
      unsigned u5 = *(const unsigned*)(ftb + (size_t)s5 * 512 + offb);
      unsigned u6 = *(const unsigned*)(ftb + (size_t)s6 * 512 + offb);
      unsigned u7 = *(const unsigned*)(ftb + (size_t)s7 * 512 + offb);
      f32x2 w0 = wl2[nh][head][kk];
      f32x2 w1 = wl2[nh][head][kk + 1];
      f32x2 w2 = wl2[nh][head][kk + 2];
      f32x2 w3 = wl2[nh][head][kk + 3];
      f32x2 w4 = wl2[nh][head][kk + 4];
      f32x2 w5 = wl2[nh][head][kk + 5];
      f32x2 w6 = wl2[nh][head][kk + 6];
      f32x2 w7 = wl2[nh][head][kk + 7];
      acc0 = __builtin_elementwise_fma(bf2(u0), w0, acc0);
      acc1 = __builtin_elementwise_fma(bf2(u1), w1, acc1);
      acc0 = __builtin_elementwise_fma(bf2(u2), w2, acc0);
      acc1 = __builtin_elementwise_fma(bf2(u3), w3, acc1);
      acc0 = __builtin_elementwise_fma(bf2(u4), w4, acc0);
      acc1 = __builtin_elementwise_fma(bf2(u5), w5, acc1);
      acc0 = __builtin_elementwise_fma(bf2(u6), w6, acc0);
      acc1 = __builtin_elementwise_fma(bf2(u7), w7, acc1);
    }
    for (; kk + 4 <= rem; kk += 4) {
      int s0 = __builtin_amdgcn_readlane(sv, kk);
      int s1 = __builtin_amdgcn_readlane(sv, kk + 1);
      int s2 = __builtin_amdgcn_readlane(sv, kk + 2);
      int s3 = __builtin_amdgcn_readlane(sv, kk + 3);
      unsigned u0 = *(const unsigned*)(ftb + (size_t)s0 * 512 + offb);
      unsigned u1 = *(const unsigned*)(ftb + (size_t)s1 * 512 + offb);
      unsigned u2 = *(const unsigned*)(ftb + (size_t)s2 * 512 + offb);
      unsigned u3 = *(const unsigned*)(ftb + (size_t)s3 * 512 + offb);
      f32x2 w0 = wl2[nh][head][kk];
      f32x2 w1 = wl2[nh][head][kk + 1];
      f32x2 w2 = wl2[nh][head][kk + 2];
      f32x2 w3 = wl2[nh][head][kk + 3];
      acc0 = __builtin_elementwise_fma(bf2(u0), w0, acc0);
      acc1 = __builtin_elementwise_fma(bf2(u1), w1, acc1);
      acc0 = __builtin_elementwise_fma(bf2(u2), w2, acc0);
      acc1 = __builtin_elementwise_fma(bf2(u3), w3, acc1);
    }
    for (; kk < rem; ++kk) {
      int s0 = __builtin_amdgcn_readlane(sv, kk);
      unsigned u0 = *(const unsigned*)(ftb + (size_t)s0 * 512 + offb);
      f32x2 w0 = wl2[nh][head][kk];
      acc0 = __builtin_elementwise_fma(bf2(u0), w0, acc0);
    }
  }
#pragma unroll
  for (int m = 16; m; m >>= 1) denp += __shfl_xor(denp, m);

  f32x2 res = {0.f, 0.f};
  if (end > beg) {
    float rd = 1.f / denp;
    res.x = (acc0.x + acc1.x) * rd;
    res.y = (acc0.y + acc1.y) * rd;
  }

  unsigned pu = *(const unsigned*)((const char*)prev + (size_t)n * 512 + offb);
  f32x2 pv = bf2(pu);

  if (LAYER == 0) {
    float vx = res.x + pv.x;
    float vy = res.y + pv.y;
    vx = vx > 0.f ? vx : (__expf(vx) - 1.0f);  // ELU
    vy = vy > 0.f ? vy : (__expf(vy) - 1.0f);
    bf16_2 o = {(__bf16)vx, (__bf16)vy};
    *(bf16_2*)((char*)outb + (size_t)n * 512 + offb) = o;
  } else {
    f32x2 bv = *(const f32x2*)(bias + head * 64 + 2 * k32);
    f32x2 rv = {res.x + pv.x + bv.x, res.y + pv.y + bv.y};
    red2[nh][head][k32] = rv;
    __syncthreads();
    if ((wav & 1) == 0 && hf == 0) {
      f32x2 a = red2[nh][0][k32];
      f32x2 b = red2[nh][1][k32];
      f32x2 c = red2[nh][2][k32];
      f32x2 d = red2[nh][3][k32];
      f32x2 s = {0.25f * (a.x + b.x + c.x + d.x), 0.25f * (a.y + b.y + c.y + d.y)};
      *(f32x2*)(outf + (size_t)n * 64 + 2 * k32) = s;
    }
  }
}

// ---------------------------------------------------------------- launch
extern "C" void kernel_launch(void* const* d_in, const int* in_sizes, int n_in,
                              void* d_out, int out_size, void* d_ws, size_t ws_size,
                              hipStream_t stream) {
  const float* features  = (const float*)d_in[0];
  const float* edge_feat = (const float*)d_in[1];
  const int*   src       = (const int*)d_in[2];
  const int*   dst       = (const int*)d_in[3];
  const float* W0    = (const float*)d_in[4];
  const float* We0   = (const float*)d_in[5];
  const float* al0   = (const float*)d_in[6];
  const float* ar0   = (const float*)d_in[7];
  const float* ae0   = (const float*)d_in[8];
  const float* b0    = (const float*)d_in[9];
  const float* Wres0 = (const float*)d_in[10];
  const float* W1    = (const float*)d_in[11];
  const float* We1   = (const float*)d_in[12];
  const float* al1   = (const float*)d_in[13];
  const float* ar1   = (const float*)d_in[14];
  const float* ae1   = (const float*)d_in[15];
  const float* b1    = (const float*)d_in[16];
  float* out = (float*)d_out;

  char* ws = (char*)d_ws;
  size_t o = 0;
  auto alloc = [&](size_t bytes) {
    void* p = ws + o;
    o = (o + bytes + 255) & ~(size_t)255;
    return p;
  };
  int*    cnt      = (int*)alloc((size_t)NN * 4);
  int*    scanbuf  = (int*)alloc((size_t)NN * 4);
  int*    blocksum = (int*)alloc(256 * 4);
  int*    blockoff = (int*)alloc(256 * 4);
  int*    off      = (int*)alloc((size_t)(NN + 1) * 4);
  int*    cur      = (int*)alloc((size_t)NN * 4);
  int*    srcc     = (int*)alloc((size_t)EE * 4);
  int*    pose     = (int*)alloc((size_t)EE * 4);
  float*  eeo0     = (float*)alloc((size_t)EE * 4 * 4);
  float*  eeo1     = (float*)alloc((size_t)EE * 4 * 4);
  float*  wcsr     = (float*)alloc((size_t)EE * 4 * 4);
  float*  el       = (float*)alloc((size_t)NN * 4 * 4);
  float*  er       = (float*)alloc((size_t)NN * 4 * 4);
  float*  Ve0      = (float*)alloc(256 * 4);
  float*  Ve1      = (float*)alloc(256 * 4);
  __bf16* Bt0      = (__bf16*)alloc((size_t)512 * 64 * 2);
  __bf16* Bt1      = (__bf16*)alloc((size_t)256 * 256 * 2);
  __bf16* fbf      = (__bf16*)alloc((size_t)NN * 64 * 2);
  __bf16* ft       = (__bf16*)alloc((size_t)NN * 256 * 2);
  __bf16* base     = (__bf16*)alloc((size_t)NN * 256 * 2);  // h1 aliases base
  __bf16* h1       = base;

  const int EB = (EE + 255) / 256;   // 1563
  const int MG = (NN + 63) / 64;     // 782

  hipMemsetAsync(cnt, 0, (size_t)NN * 4, stream);
  prep_kernel<<<1949 + EB, 256, 0, stream>>>(features, fbf, W0, Wres0, Bt0, W1, Bt1,
                                             We0, ae0, Ve0, We1, ae1, Ve1, dst, cnt);

  // cooperative CSR-build + eek (one dispatch, grid-wide syncs between phases)
  {
    void* args[] = {(void*)&cnt, (void*)&scanbuf, (void*)&blocksum, (void*)&blockoff,
                    (void*)&off, (void*)&cur, (void*)&src, (void*)&dst,
                    (void*)&srcc, (void*)&pose, (void*)&edge_feat, (void*)&Ve0,
                    (void*)&Ve1, (void*)&eeo0, (void*)&eeo1};
    hipLaunchCooperativeKernel((const void*)csr_eek_kernel, dim3(COOPB), dim3(256),
                               args, 0, stream);
  }

  // ---- layer 0
  gemm_kernel<<<dim3(MG, 8), 256, 0, stream>>>(fbf, Bt0, ft, base, b0, al0, ar0, el, er, NN, 64);
  wk_kernel<<<EB, 256, 0, stream>>>(src, dst, pose, eeo0, el, er, wcsr);
  agg_kernel<0><<<NN / 2, 256, 0, stream>>>(off, srcc, wcsr, ft, base, nullptr, h1, nullptr);

  // ---- layer 1
  gemm_kernel<<<dim3(MG, 4), 256, 0, stream>>>(h1, Bt1, ft, nullptr, nullptr, al1, ar1, el, er, NN, 256);
  wk_kernel<<<EB, 256, 0, stream>>>(src, dst, pose, eeo1, el, er, wcsr);
  agg_kernel<1><<<NN / 2, 256, 0, stream>>>(off, srcc, wcsr, ft, h1, b1, nullptr, out);
}

// Round 4
// 387.596 us; speedup vs baseline: 1.9190x; 1.9190x over previous
//
#include <hip/hip_runtime.h>
#include <hip/hip_bf16.h>

#define NN 50000
#define EE 400000
#define NB 196  // ceil(NN/256)

typedef __bf16 bf16_8 __attribute__((ext_vector_type(8)));
typedef __bf16 bf16_2 __attribute__((ext_vector_type(2)));
typedef float f32x4 __attribute__((ext_vector_type(4)));
typedef float f32x2 __attribute__((ext_vector_type(2)));

// unpack 2 packed bf16 (one dword) -> 2 f32 (exact, 2 bitops)
__device__ inline f32x2 bf2(unsigned u) {
  f32x2 r;
  r.x = __uint_as_float(u << 16);
  r.y = __uint_as_float(u & 0xffff0000u);
  return r;
}

// ---------------------------------------------------------------- prep (fused)
// [0,1563): f2b; [1563,1691): tr0; [1691,1947): tr1; 1947: ve0; 1948: ve1;
// [1949, 1949+1563): degree count (cnt zeroed by memset before launch)
__global__ __launch_bounds__(256) void prep_kernel(
    const float* __restrict__ features, __bf16* __restrict__ fbf,
    const float* __restrict__ W0, const float* __restrict__ Wres0, __bf16* __restrict__ Bt0,
    const float* __restrict__ W1, __bf16* __restrict__ Bt1,
    const float* __restrict__ We0, const float* __restrict__ ae0, float* __restrict__ Ve0,
    const float* __restrict__ We1, const float* __restrict__ ae1, float* __restrict__ Ve1,
    const int* __restrict__ dst, int* __restrict__ cnt) {
  int b = blockIdx.x;
  int t = threadIdx.x;
  if (b < 1563) {                       // fp32 -> bf16, 8 elems/thread
    int i = b * 256 + t;
    if (i < NN * 64 / 8) {
      const float4* p = (const float4*)features + (size_t)i * 2;
      float4 a = p[0], c = p[1];
      bf16_8 v = {(__bf16)a.x, (__bf16)a.y, (__bf16)a.z, (__bf16)a.w,
                  (__bf16)c.x, (__bf16)c.y, (__bf16)c.z, (__bf16)c.w};
      *(bf16_8*)(fbf + (size_t)i * 8) = v;
    }
  } else if (b < 1563 + 128) {          // Bt0 (512x64): W0^T | Wres0^T
    int idx = (b - 1563) * 256 + t;
    int j = idx >> 6, k = idx & 63;
    float v = (j < 256) ? W0[k * 256 + j] : Wres0[k * 256 + (j - 256)];
    Bt0[idx] = (__bf16)v;
  } else if (b < 1563 + 128 + 256) {    // Bt1 (256x256) = W1^T
    int idx = (b - 1563 - 128) * 256 + t;
    int j = idx >> 8, k = idx & 255;
    Bt1[idx] = (__bf16)W1[k * 256 + j];
  } else if (b == 1947) {               // Ve0
    int f = t >> 2, h = t & 3;
    float s = 0.f;
    for (int d = 0; d < 64; ++d) s += We0[f * 256 + h * 64 + d] * ae0[h * 64 + d];
    Ve0[f * 4 + h] = s;
  } else if (b == 1948) {               // Ve1
    int f = t >> 2, h = t & 3;
    float s = 0.f;
    for (int d = 0; d < 64; ++d) s += We1[f * 256 + h * 64 + d] * ae1[h * 64 + d];
    Ve1[f * 4 + h] = s;
  } else {                              // degree count
    int e = (b - 1949) * 256 + t;
    if (e < EE) atomicAdd(&cnt[dst[e]], 1);
  }
}

// ---------------------------------------------------------------- CSR scan (2-phase)
__global__ __launch_bounds__(256) void scan1_kernel(const int* __restrict__ cnt,
                                                    int* __restrict__ scanbuf,
                                                    int* __restrict__ blocksum) {
  __shared__ int s[256];
  int t = threadIdx.x;
  int idx = blockIdx.x * 256 + t;
  int c = (idx < NN) ? cnt[idx] : 0;
  s[t] = c;
  __syncthreads();
  for (int d = 1; d < 256; d <<= 1) {
    int v = (t >= d) ? s[t - d] : 0;
    __syncthreads();
    s[t] += v;
    __syncthreads();
  }
  if (idx < NN) scanbuf[idx] = s[t];
  if (t == 255) blocksum[blockIdx.x] = s[255];
}

// merged scan2+scan3: every block redundantly scans the 196 block sums (cheap),
// then emits off/cur for its 256 nodes.
__global__ __launch_bounds__(256) void scan23_kernel(const int* __restrict__ scanbuf,
                                                     const int* __restrict__ cnt,
                                                     const int* __restrict__ blocksum,
                                                     int* __restrict__ off,
                                                     int* __restrict__ cur) {
  __shared__ int s[256];
  int t = threadIdx.x;
  int c = (t < NB) ? blocksum[t] : 0;
  s[t] = c;
  __syncthreads();
  for (int d = 1; d < 256; d <<= 1) {
    int v = (t >= d) ? s[t - d] : 0;
    __syncthreads();
    s[t] += v;
    __syncthreads();
  }
  int boff = (blockIdx.x > 0) ? s[blockIdx.x - 1] : 0;
  int idx = blockIdx.x * 256 + t;
  if (idx < NN) {
    int o = boff + scanbuf[idx] - cnt[idx];
    off[idx] = o;
    cur[idx] = o;
  }
  if (idx == 0) off[NN] = EE;
}

// ---------------------------------------------------------------- fill + eek (fused)
// 64 edges per block (EE % 64 == 0). Phase A (t<64): CSR fill via atomics; slot
// kept in LDS (no global pose array). Phase B: ee dot-products, 4 lanes/row,
// written DIRECTLY IN CSR ORDER via posh. V tables stored padded
// (p = d*4+h + (d>>4)*4) so the 4 sub-lanes of a quad hit different banks
// (was a 4-way conflict, 9.6M cycles measured in r3).
__global__ __launch_bounds__(256) void filleek_kernel(
    const int* __restrict__ src, const int* __restrict__ dst,
    int* __restrict__ cur, int* __restrict__ srcc,
    const float* __restrict__ ef, const float* __restrict__ Ve0,
    const float* __restrict__ Ve1, float* __restrict__ eeo0c,
    float* __restrict__ eeo1c) {
  __shared__ float V0[272], V1[272];
  __shared__ int posh[64];
  int t = threadIdx.x;
  int b = blockIdx.x;
  if (t < 64) {
    int e = b * 64 + t;
    int p = atomicAdd(&cur[dst[e]], 1);
    srcc[p] = src[e];
    posh[t] = p;
  }
  V0[t + (t >> 6) * 4] = Ve0[t];
  V1[t + (t >> 6) * 4] = Ve1[t];
  __syncthreads();
  int r = t >> 2, sub = t & 3;
  int e = b * 64 + r;
  float a0 = 0, a1 = 0, a2 = 0, a3 = 0;
  float c0 = 0, c1 = 0, c2 = 0, c3 = 0;
  const float* row = ef + (size_t)e * 64 + sub * 16;
#pragma unroll
  for (int i = 0; i < 16; i += 4) {
    float4 v = *(const float4*)(row + i);
    float xs[4] = {v.x, v.y, v.z, v.w};
#pragma unroll
    for (int j = 0; j < 4; ++j) {
      float x = xs[j];
      int idx = (sub * 16 + i + j) * 4 + sub * 4;  // padded V layout
      a0 += x * V0[idx + 0]; a1 += x * V0[idx + 1];
      a2 += x * V0[idx + 2]; a3 += x * V0[idx + 3];
      c0 += x * V1[idx + 0]; c1 += x * V1[idx + 1];
      c2 += x * V1[idx + 2]; c3 += x * V1[idx + 3];
    }
  }
#pragma unroll
  for (int o = 1; o < 4; o <<= 1) {
    a0 += __shfl_xor(a0, o); a1 += __shfl_xor(a1, o);
    a2 += __shfl_xor(a2, o); a3 += __shfl_xor(a3, o);
    c0 += __shfl_xor(c0, o); c1 += __shfl_xor(c1, o);
    c2 += __shfl_xor(c2, o); c3 += __shfl_xor(c3, o);
  }
  if (sub == 0) {
    int p = posh[r];
    float4 u; u.x = a0; u.y = a1; u.z = a2; u.w = a3;
    float4 w; w.x = c0; w.y = c1; w.z = c2; w.w = c3;
    *(float4*)(eeo0c + (size_t)p * 4) = u;
    *(float4*)(eeo1c + (size_t)p * 4) = w;
  }
}

// ---------------------------------------------------------------- MFMA GEMM
// C[M x NC] = A @ B, Bt: NC x K row-major. cols<256 -> ft (bf16) + fused el/er;
// cols>=256 -> base = val + bias[col-256] (layer 0 residual).
#define LDK 40
__global__ __launch_bounds__(256) void gemm_kernel(const __bf16* __restrict__ A,
                                                   const __bf16* __restrict__ Bt,
                                                   __bf16* __restrict__ ft,
                                                   __bf16* __restrict__ base,
                                                   const float* __restrict__ bias,
                                                   const float* __restrict__ al,
                                                   const float* __restrict__ ar,
                                                   float* __restrict__ el,
                                                   float* __restrict__ er,
                                                   int M, int K) {
  __shared__ __align__(16) __bf16 Al[64 * LDK];
  __shared__ __align__(16) __bf16 Bl[64 * LDK];
  int tid = threadIdx.x;
  int wav = tid >> 6, lane = tid & 63;
  int quad = lane >> 4, l16 = lane & 15;
  int bm = blockIdx.x * 64;
  int bn = blockIdx.y * 64;
  int sr = tid >> 2;
  int sk = (tid & 3) << 3;

  f32x4 acc[4] = {{0, 0, 0, 0}, {0, 0, 0, 0}, {0, 0, 0, 0}, {0, 0, 0, 0}};

  for (int k0 = 0; k0 < K; k0 += 32) {
    uint4 av = {0, 0, 0, 0};
    int arow = bm + sr;
    if (arow < M) av = *(const uint4*)(A + (size_t)arow * K + k0 + sk);
    uint4 bv = *(const uint4*)(Bt + (size_t)(bn + sr) * K + k0 + sk);
    __syncthreads();
    *(uint4*)&Al[sr * LDK + sk] = av;
    *(uint4*)&Bl[sr * LDK + sk] = bv;
    __syncthreads();
    bf16_8 af = *(const bf16_8*)&Al[(wav * 16 + l16) * LDK + quad * 8];
#pragma unroll
    for (int nt = 0; nt < 4; ++nt) {
      bf16_8 bf = *(const bf16_8*)&Bl[(nt * 16 + l16) * LDK + quad * 8];
      acc[nt] = __builtin_amdgcn_mfma_f32_16x16x32_bf16(af, bf, acc[nt], 0, 0, 0);
    }
  }

  int row0 = bm + wav * 16 + quad * 4;

  // fused el/er for head hb = bn/64 (cols < 256 only)
  if (bn < 256) {
    int hb = bn >> 6;
#pragma unroll
    for (int r = 0; r < 4; ++r) {
      float pl = 0.f, pr = 0.f;
#pragma unroll
      for (int nt = 0; nt < 4; ++nt) {
        float v = acc[nt][r];
        int d = nt * 16 + l16;
        pl += v * al[hb * 64 + d];
        pr += v * ar[hb * 64 + d];
      }
#pragma unroll
      for (int o2 = 8; o2 > 0; o2 >>= 1) {
        pl += __shfl_xor(pl, o2);
        pr += __shfl_xor(pr, o2);
      }
      int row = row0 + r;
      if (l16 == 0 && row < M) {
        el[row * 4 + hb] = pl;
        er[row * 4 + hb] = pr;
      }
    }
  }

#pragma unroll
  for (int nt = 0; nt < 4; ++nt) {
    int col = bn + nt * 16 + l16;
#pragma unroll
    for (int r = 0; r < 4; ++r) {
      int row = row0 + r;
      if (row < M) {
        float v = acc[nt][r];
        if (col < 256)
          ft[(size_t)row * 256 + col] = (__bf16)v;
        else
          base[(size_t)row * 256 + (col - 256)] = (__bf16)(v + bias[col - 256]);
      }
    }
  }
}

// ---------------------------------------------------------------- agg
// 2 nodes per block (node = wav>>1); 2 waves per node; each wave covers 2 heads
// (head = (wav&1)*2 + lane/32), each lane holds a bf16x2 dim-pair -> packed
// f32x2 FMA. Per-chunk (32 edges): srcc chunk load + INLINE weight compute
// w = exp(leaky(el[s] + er[n] + ee_csr)) (replaces the standalone wk pass;
// one 4B el-gather + 1 exp per (edge,head), ee read coalesced in CSR order).
// Weights staged DUPLICATED into LDS as {w,w} (ds_read_b64 B-operand, zero
// VALU in inner loop). Denominator from each lane's own wv, one shfl reduce.
// Gather unrolled x8 for memory-level parallelism (random-line latency-bound).
template <int LAYER>
__global__ __launch_bounds__(256) void agg_kernel(const int* __restrict__ off,
                                                  const int* __restrict__ srcc,
                                                  const float* __restrict__ eeoc,
                                                  const float* __restrict__ el,
                                                  const float* __restrict__ er,
                                                  const __bf16* __restrict__ ft,
                                                  const __bf16* prev,
                                                  const float* __restrict__ bias,
                                                  __bf16* outb,
                                                  float* __restrict__ outf) {
  __shared__ f32x2 wl2[2][4][32];
  __shared__ f32x2 red2[2][4][32];
  int t = threadIdx.x;
  int wav = t >> 6, lane = t & 63;
  int nh = wav >> 1;            // node half within block
  int hf = lane >> 5;           // half-wave
  int head = ((wav & 1) << 1) + hf;
  int k32 = lane & 31;
  int n = blockIdx.x * 2 + nh;
  int beg = off[n], end = off[n + 1];
  float ern = er[n * 4 + head];
  int offb = head * 128 + k32 * 4;  // byte offset within 512B ft row

  const char* ftb = (const char*)ft;
  f32x2 acc0 = {0.f, 0.f}, acc1 = {0.f, 0.f};
  float denp = 0.f;

  for (int c = beg; c < end; c += 32) {
    int rem = end - c;
    if (rem > 32) rem = 32;
    int sv = 0;
    float wv = 0.f;
    if (k32 < rem) {
      sv = srcc[c + k32];
      float z = el[sv * 4 + head] + ern + eeoc[(size_t)(c + k32) * 4 + head];
      wv = __expf(z > 0.f ? z : 0.2f * z);
    }
    denp += wv;
    f32x2 wd = {wv, wv};
    wl2[nh][head][k32] = wd;
    int kk = 0;
    for (; kk + 8 <= rem; kk += 8) {
      int s0 = __builtin_amdgcn_readlane(sv, kk);
      int s1 = __builtin_amdgcn_readlane(sv, kk + 1);
      int s2 = __builtin_amdgcn_readlane(sv, kk + 2);
      int s3 = __builtin_amdgcn_readlane(sv, kk + 3);
      int s4 = __builtin_amdgcn_readlane(sv, kk + 4);
      int s5 = __builtin_amdgcn_readlane(sv, kk + 5);
      int s6 = __builtin_amdgcn_readlane(sv, kk + 6);
      int s7 = __builtin_amdgcn_readlane(sv, kk + 7);
      unsigned u0 = *(const unsigned*)(ftb + (size_t)s0 * 512 + offb);
      unsigned u1 = *(const unsigned*)(ftb + (size_t)s1 * 512 + offb);
      unsigned u2 = *(const unsigned*)(ftb + (size_t)s2 * 512 + offb);
      unsigned u3 = *(const unsigned*)(ftb + (size_t)s3 * 512 + offb);
      unsigned u4 = *(const unsigned*)(ftb + (size_t)s4 * 512 + offb);
      unsigned u5 = *(const unsigned*)(ftb + (size_t)s5 * 512 + offb);
      unsigned u6 = *(const unsigned*)(ftb + (size_t)s6 * 512 + offb);
      unsigned u7 = *(const unsigned*)(ftb + (size_t)s7 * 512 + offb);
      f32x2 w0 = wl2[nh][head][kk];
      f32x2 w1 = wl2[nh][head][kk + 1];
      f32x2 w2 = wl2[nh][head][kk + 2];
      f32x2 w3 = wl2[nh][head][kk + 3];
      f32x2 w4 = wl2[nh][head][kk + 4];
      f32x2 w5 = wl2[nh][head][kk + 5];
      f32x2 w6 = wl2[nh][head][kk + 6];
      f32x2 w7 = wl2[nh][head][kk + 7];
      acc0 = __builtin_elementwise_fma(bf2(u0), w0, acc0);
      acc1 = __builtin_elementwise_fma(bf2(u1), w1, acc1);
      acc0 = __builtin_elementwise_fma(bf2(u2), w2, acc0);
      acc1 = __builtin_elementwise_fma(bf2(u3), w3, acc1);
      acc0 = __builtin_elementwise_fma(bf2(u4), w4, acc0);
      acc1 = __builtin_elementwise_fma(bf2(u5), w5, acc1);
      acc0 = __builtin_elementwise_fma(bf2(u6), w6, acc0);
      acc1 = __builtin_elementwise_fma(bf2(u7), w7, acc1);
    }
    for (; kk + 4 <= rem; kk += 4) {
      int s0 = __builtin_amdgcn_readlane(sv, kk);
      int s1 = __builtin_amdgcn_readlane(sv, kk + 1);
      int s2 = __builtin_amdgcn_readlane(sv, kk + 2);
      int s3 = __builtin_amdgcn_readlane(sv, kk + 3);
      unsigned u0 = *(const unsigned*)(ftb + (size_t)s0 * 512 + offb);
      unsigned u1 = *(const unsigned*)(ftb + (size_t)s1 * 512 + offb);
      unsigned u2 = *(const unsigned*)(ftb + (size_t)s2 * 512 + offb);
      unsigned u3 = *(const unsigned*)(ftb + (size_t)s3 * 512 + offb);
      f32x2 w0 = wl2[nh][head][kk];
      f32x2 w1 = wl2[nh][head][kk + 1];
      f32x2 w2 = wl2[nh][head][kk + 2];
      f32x2 w3 = wl2[nh][head][kk + 3];
      acc0 = __builtin_elementwise_fma(bf2(u0), w0, acc0);
      acc1 = __builtin_elementwise_fma(bf2(u1), w1, acc1);
      acc0 = __builtin_elementwise_fma(bf2(u2), w2, acc0);
      acc1 = __builtin_elementwise_fma(bf2(u3), w3, acc1);
    }
    for (; kk < rem; ++kk) {
      int s0 = __builtin_amdgcn_readlane(sv, kk);
      unsigned u0 = *(const unsigned*)(ftb + (size_t)s0 * 512 + offb);
      f32x2 w0 = wl2[nh][head][kk];
      acc0 = __builtin_elementwise_fma(bf2(u0), w0, acc0);
    }
  }
#pragma unroll
  for (int m = 16; m; m >>= 1) denp += __shfl_xor(denp, m);

  f32x2 res = {0.f, 0.f};
  if (end > beg) {
    float rd = 1.f / denp;
    res.x = (acc0.x + acc1.x) * rd;
    res.y = (acc0.y + acc1.y) * rd;
  }

  unsigned pu = *(const unsigned*)((const char*)prev + (size_t)n * 512 + offb);
  f32x2 pv = bf2(pu);

  if (LAYER == 0) {
    float vx = res.x + pv.x;
    float vy = res.y + pv.y;
    vx = vx > 0.f ? vx : (__expf(vx) - 1.0f);  // ELU
    vy = vy > 0.f ? vy : (__expf(vy) - 1.0f);
    bf16_2 o = {(__bf16)vx, (__bf16)vy};
    *(bf16_2*)((char*)outb + (size_t)n * 512 + offb) = o;
  } else {
    f32x2 bv = *(const f32x2*)(bias + head * 64 + 2 * k32);
    f32x2 rv = {res.x + pv.x + bv.x, res.y + pv.y + bv.y};
    red2[nh][head][k32] = rv;
    __syncthreads();
    if ((wav & 1) == 0 && hf == 0) {
      f32x2 a = red2[nh][0][k32];
      f32x2 b = red2[nh][1][k32];
      f32x2 c = red2[nh][2][k32];
      f32x2 d = red2[nh][3][k32];
      f32x2 s = {0.25f * (a.x + b.x + c.x + d.x), 0.25f * (a.y + b.y + c.y + d.y)};
      *(f32x2*)(outf + (size_t)n * 64 + 2 * k32) = s;
    }
  }
}

// ---------------------------------------------------------------- launch
extern "C" void kernel_launch(void* const* d_in, const int* in_sizes, int n_in,
                              void* d_out, int out_size, void* d_ws, size_t ws_size,
                              hipStream_t stream) {
  const float* features  = (const float*)d_in[0];
  const float* edge_feat = (const float*)d_in[1];
  const int*   src       = (const int*)d_in[2];
  const int*   dst       = (const int*)d_in[3];
  const float* W0    = (const float*)d_in[4];
  const float* We0   = (const float*)d_in[5];
  const float* al0   = (const float*)d_in[6];
  const float* ar0   = (const float*)d_in[7];
  const float* ae0   = (const float*)d_in[8];
  const float* b0    = (const float*)d_in[9];
  const float* Wres0 = (const float*)d_in[10];
  const float* W1    = (const float*)d_in[11];
  const float* We1   = (const float*)d_in[12];
  const float* al1   = (const float*)d_in[13];
  const float* ar1   = (const float*)d_in[14];
  const float* ae1   = (const float*)d_in[15];
  const float* b1    = (const float*)d_in[16];
  float* out = (float*)d_out;

  char* ws = (char*)d_ws;
  size_t o = 0;
  auto alloc = [&](size_t bytes) {
    void* p = ws + o;
    o = (o + bytes + 255) & ~(size_t)255;
    return p;
  };
  int*    cnt      = (int*)alloc((size_t)NN * 4);
  int*    scanbuf  = (int*)alloc((size_t)NN * 4);
  int*    blocksum = (int*)alloc(256 * 4);
  int*    off      = (int*)alloc((size_t)(NN + 1) * 4);
  int*    cur      = (int*)alloc((size_t)NN * 4);
  int*    srcc     = (int*)alloc((size_t)EE * 4);
  float*  eeo0c    = (float*)alloc((size_t)EE * 4 * 4);
  float*  eeo1c    = (float*)alloc((size_t)EE * 4 * 4);
  float*  el       = (float*)alloc((size_t)NN * 4 * 4);
  float*  er       = (float*)alloc((size_t)NN * 4 * 4);
  float*  Ve0      = (float*)alloc(256 * 4);
  float*  Ve1      = (float*)alloc(256 * 4);
  __bf16* Bt0      = (__bf16*)alloc((size_t)512 * 64 * 2);
  __bf16* Bt1      = (__bf16*)alloc((size_t)256 * 256 * 2);
  __bf16* fbf      = (__bf16*)alloc((size_t)NN * 64 * 2);
  __bf16* ft       = (__bf16*)alloc((size_t)NN * 256 * 2);
  __bf16* base     = (__bf16*)alloc((size_t)NN * 256 * 2);  // h1 aliases base
  __bf16* h1       = base;

  const int EB = (EE + 255) / 256;   // 1563
  const int MG = (NN + 63) / 64;     // 782

  hipMemsetAsync(cnt, 0, (size_t)NN * 4, stream);
  prep_kernel<<<1949 + EB, 256, 0, stream>>>(features, fbf, W0, Wres0, Bt0, W1, Bt1,
                                             We0, ae0, Ve0, We1, ae1, Ve1, dst, cnt);
  scan1_kernel<<<NB, 256, 0, stream>>>(cnt, scanbuf, blocksum);
  scan23_kernel<<<NB, 256, 0, stream>>>(scanbuf, cnt, blocksum, off, cur);
  filleek_kernel<<<EE / 64, 256, 0, stream>>>(src, dst, cur, srcc, edge_feat,
                                              Ve0, Ve1, eeo0c, eeo1c);

  // ---- layer 0
  gemm_kernel<<<dim3(MG, 8), 256, 0, stream>>>(fbf, Bt0, ft, base, b0, al0, ar0, el, er, NN, 64);
  agg_kernel<0><<<NN / 2, 256, 0, stream>>>(off, srcc, eeo0c, el, er, ft, base, nullptr, h1, nullptr);

  // ---- layer 1
  gemm_kernel<<<dim3(MG, 4), 256, 0, stream>>>(h1, Bt1, ft, nullptr, nullptr, al1, ar1, el, er, NN, 256);
  agg_kernel<1><<<NN / 2, 256, 0, stream>>>(off, srcc, eeo1c, el, er, ft, h1, b1, nullptr, out);
}

// Round 5
// 368.378 us; speedup vs baseline: 2.0191x; 1.0522x over previous
//
#include <hip/hip_runtime.h>
#include <hip/hip_bf16.h>

#define NN 50000
#define EE 400000
#define NB 196  // ceil(NN/256)

typedef __bf16 bf16_8 __attribute__((ext_vector_type(8)));
typedef __bf16 bf16_4 __attribute__((ext_vector_type(4)));
typedef __bf16 bf16_2 __attribute__((ext_vector_type(2)));
typedef float f32x4 __attribute__((ext_vector_type(4)));
typedef float f32x2 __attribute__((ext_vector_type(2)));

// unpack 2 packed bf16 (one dword) -> 2 f32 (exact, 2 bitops)
__device__ inline f32x2 bf2(unsigned u) {
  f32x2 r;
  r.x = __uint_as_float(u << 16);
  r.y = __uint_as_float(u & 0xffff0000u);
  return r;
}

// ---------------------------------------------------------------- prep (fused)
// [0,1563): f2b; [1563,1691): tr0; [1691,1947): tr1; 1947: ve0; 1948: ve1;
// [1949, 1949+1563): degree count (cnt zeroed by memset before launch)
__global__ __launch_bounds__(256) void prep_kernel(
    const float* __restrict__ features, __bf16* __restrict__ fbf,
    const float* __restrict__ W0, const float* __restrict__ Wres0, __bf16* __restrict__ Bt0,
    const float* __restrict__ W1, __bf16* __restrict__ Bt1,
    const float* __restrict__ We0, const float* __restrict__ ae0, float* __restrict__ Ve0,
    const float* __restrict__ We1, const float* __restrict__ ae1, float* __restrict__ Ve1,
    const int* __restrict__ dst, int* __restrict__ cnt) {
  int b = blockIdx.x;
  int t = threadIdx.x;
  if (b < 1563) {                       // fp32 -> bf16, 8 elems/thread
    int i = b * 256 + t;
    if (i < NN * 64 / 8) {
      const float4* p = (const float4*)features + (size_t)i * 2;
      float4 a = p[0], c = p[1];
      bf16_8 v = {(__bf16)a.x, (__bf16)a.y, (__bf16)a.z, (__bf16)a.w,
                  (__bf16)c.x, (__bf16)c.y, (__bf16)c.z, (__bf16)c.w};
      *(bf16_8*)(fbf + (size_t)i * 8) = v;
    }
  } else if (b < 1563 + 128) {          // Bt0 (512x64): W0^T | Wres0^T
    int idx = (b - 1563) * 256 + t;
    int j = idx >> 6, k = idx & 63;
    float v = (j < 256) ? W0[k * 256 + j] : Wres0[k * 256 + (j - 256)];
    Bt0[idx] = (__bf16)v;
  } else if (b < 1563 + 128 + 256) {    // Bt1 (256x256) = W1^T
    int idx = (b - 1563 - 128) * 256 + t;
    int j = idx >> 8, k = idx & 255;
    Bt1[idx] = (__bf16)W1[k * 256 + j];
  } else if (b == 1947) {               // Ve0
    int f = t >> 2, h = t & 3;
    float s = 0.f;
    for (int d = 0; d < 64; ++d) s += We0[f * 256 + h * 64 + d] * ae0[h * 64 + d];
    Ve0[f * 4 + h] = s;
  } else if (b == 1948) {               // Ve1
    int f = t >> 2, h = t & 3;
    float s = 0.f;
    for (int d = 0; d < 64; ++d) s += We1[f * 256 + h * 64 + d] * ae1[h * 64 + d];
    Ve1[f * 4 + h] = s;
  } else {                              // degree count
    int e = (b - 1949) * 256 + t;
    if (e < EE) atomicAdd(&cnt[dst[e]], 1);
  }
}

// ---------------------------------------------------------------- CSR scan (2-phase)
__global__ __launch_bounds__(256) void scan1_kernel(const int* __restrict__ cnt,
                                                    int* __restrict__ scanbuf,
                                                    int* __restrict__ blocksum) {
  __shared__ int s[256];
  int t = threadIdx.x;
  int idx = blockIdx.x * 256 + t;
  int c = (idx < NN) ? cnt[idx] : 0;
  s[t] = c;
  __syncthreads();
  for (int d = 1; d < 256; d <<= 1) {
    int v = (t >= d) ? s[t - d] : 0;
    __syncthreads();
    s[t] += v;
    __syncthreads();
  }
  if (idx < NN) scanbuf[idx] = s[t];
  if (t == 255) blocksum[blockIdx.x] = s[255];
}

// merged scan2+scan3: every block redundantly scans the 196 block sums (cheap),
// then emits off/cur for its 256 nodes.
__global__ __launch_bounds__(256) void scan23_kernel(const int* __restrict__ scanbuf,
                                                     const int* __restrict__ cnt,
                                                     const int* __restrict__ blocksum,
                                                     int* __restrict__ off,
                                                     int* __restrict__ cur) {
  __shared__ int s[256];
  int t = threadIdx.x;
  int c = (t < NB) ? blocksum[t] : 0;
  s[t] = c;
  __syncthreads();
  for (int d = 1; d < 256; d <<= 1) {
    int v = (t >= d) ? s[t - d] : 0;
    __syncthreads();
    s[t] += v;
    __syncthreads();
  }
  int boff = (blockIdx.x > 0) ? s[blockIdx.x - 1] : 0;
  int idx = blockIdx.x * 256 + t;
  if (idx < NN) {
    int o = boff + scanbuf[idx] - cnt[idx];
    off[idx] = o;
    cur[idx] = o;
  }
  if (idx == 0) off[NN] = EE;
}

// ---------------------------------------------------------------- fill + eek (fused)
// 64 edges per block (EE % 64 == 0). Phase A (t<64): CSR fill via atomics; slot
// kept in LDS (no global pose array). Phase B: ee dot-products, 4 lanes/row,
// written DIRECTLY IN CSR ORDER via posh. V tables stored padded
// (p = d*4+h + (d>>4)*4) so the 4 sub-lanes of a quad hit different banks
// (was a 4-way conflict, 9.6M cycles measured in r3).
__global__ __launch_bounds__(256) void filleek_kernel(
    const int* __restrict__ src, const int* __restrict__ dst,
    int* __restrict__ cur, int* __restrict__ srcc,
    const float* __restrict__ ef, const float* __restrict__ Ve0,
    const float* __restrict__ Ve1, float* __restrict__ eeo0c,
    float* __restrict__ eeo1c) {
  __shared__ float V0[272], V1[272];
  __shared__ int posh[64];
  int t = threadIdx.x;
  int b = blockIdx.x;
  if (t < 64) {
    int e = b * 64 + t;
    int p = atomicAdd(&cur[dst[e]], 1);
    srcc[p] = src[e];
    posh[t] = p;
  }
  V0[t + (t >> 6) * 4] = Ve0[t];
  V1[t + (t >> 6) * 4] = Ve1[t];
  __syncthreads();
  int r = t >> 2, sub = t & 3;
  int e = b * 64 + r;
  float a0 = 0, a1 = 0, a2 = 0, a3 = 0;
  float c0 = 0, c1 = 0, c2 = 0, c3 = 0;
  const float* row = ef + (size_t)e * 64 + sub * 16;
#pragma unroll
  for (int i = 0; i < 16; i += 4) {
    float4 v = *(const float4*)(row + i);
    float xs[4] = {v.x, v.y, v.z, v.w};
#pragma unroll
    for (int j = 0; j < 4; ++j) {
      float x = xs[j];
      int idx = (sub * 16 + i + j) * 4 + sub * 4;  // padded V layout
      a0 += x * V0[idx + 0]; a1 += x * V0[idx + 1];
      a2 += x * V0[idx + 2]; a3 += x * V0[idx + 3];
      c0 += x * V1[idx + 0]; c1 += x * V1[idx + 1];
      c2 += x * V1[idx + 2]; c3 += x * V1[idx + 3];
    }
  }
#pragma unroll
  for (int o = 1; o < 4; o <<= 1) {
    a0 += __shfl_xor(a0, o); a1 += __shfl_xor(a1, o);
    a2 += __shfl_xor(a2, o); a3 += __shfl_xor(a3, o);
    c0 += __shfl_xor(c0, o); c1 += __shfl_xor(c1, o);
    c2 += __shfl_xor(c2, o); c3 += __shfl_xor(c3, o);
  }
  if (sub == 0) {
    int p = posh[r];
    float4 u; u.x = a0; u.y = a1; u.z = a2; u.w = a3;
    float4 w; w.x = c0; w.y = c1; w.z = c2; w.w = c3;
    *(float4*)(eeo0c + (size_t)p * 4) = u;
    *(float4*)(eeo1c + (size_t)p * 4) = w;
  }
}

// ---------------------------------------------------------------- MFMA GEMM
// C[M x NC] = A @ B, Bt: NC x K row-major. cols<256 -> ft (bf16) + fused el/er;
// cols>=256 -> base = val + bias[col-256] (layer 0 residual).
#define LDK 40
__global__ __launch_bounds__(256) void gemm_kernel(const __bf16* __restrict__ A,
                                                   const __bf16* __restrict__ Bt,
                                                   __bf16* __restrict__ ft,
                                                   __bf16* __restrict__ base,
                                                   const float* __restrict__ bias,
                                                   const float* __restrict__ al,
                                                   const float* __restrict__ ar,
                                                   float* __restrict__ el,
                                                   float* __restrict__ er,
                                                   int M, int K) {
  __shared__ __align__(16) __bf16 Al[64 * LDK];
  __shared__ __align__(16) __bf16 Bl[64 * LDK];
  int tid = threadIdx.x;
  int wav = tid >> 6, lane = tid & 63;
  int quad = lane >> 4, l16 = lane & 15;
  int bm = blockIdx.x * 64;
  int bn = blockIdx.y * 64;
  int sr = tid >> 2;
  int sk = (tid & 3) << 3;

  f32x4 acc[4] = {{0, 0, 0, 0}, {0, 0, 0, 0}, {0, 0, 0, 0}, {0, 0, 0, 0}};

  for (int k0 = 0; k0 < K; k0 += 32) {
    uint4 av = {0, 0, 0, 0};
    int arow = bm + sr;
    if (arow < M) av = *(const uint4*)(A + (size_t)arow * K + k0 + sk);
    uint4 bv = *(const uint4*)(Bt + (size_t)(bn + sr) * K + k0 + sk);
    __syncthreads();
    *(uint4*)&Al[sr * LDK + sk] = av;
    *(uint4*)&Bl[sr * LDK + sk] = bv;
    __syncthreads();
    bf16_8 af = *(const bf16_8*)&Al[(wav * 16 + l16) * LDK + quad * 8];
#pragma unroll
    for (int nt = 0; nt < 4; ++nt) {
      bf16_8 bf = *(const bf16_8*)&Bl[(nt * 16 + l16) * LDK + quad * 8];
      acc[nt] = __builtin_amdgcn_mfma_f32_16x16x32_bf16(af, bf, acc[nt], 0, 0, 0);
    }
  }

  int row0 = bm + wav * 16 + quad * 4;

  // fused el/er for head hb = bn/64 (cols < 256 only)
  if (bn < 256) {
    int hb = bn >> 6;
#pragma unroll
    for (int r = 0; r < 4; ++r) {
      float pl = 0.f, pr = 0.f;
#pragma unroll
      for (int nt = 0; nt < 4; ++nt) {
        float v = acc[nt][r];
        int d = nt * 16 + l16;
        pl += v * al[hb * 64 + d];
        pr += v * ar[hb * 64 + d];
      }
#pragma unroll
      for (int o2 = 8; o2 > 0; o2 >>= 1) {
        pl += __shfl_xor(pl, o2);
        pr += __shfl_xor(pr, o2);
      }
      int row = row0 + r;
      if (l16 == 0 && row < M) {
        el[row * 4 + hb] = pl;
        er[row * 4 + hb] = pr;
      }
    }
  }

#pragma unroll
  for (int nt = 0; nt < 4; ++nt) {
    int col = bn + nt * 16 + l16;
#pragma unroll
    for (int r = 0; r < 4; ++r) {
      int row = row0 + r;
      if (row < M) {
        float v = acc[nt][r];
        if (col < 256)
          ft[(size_t)row * 256 + col] = (__bf16)v;
        else
          base[(size_t)row * 256 + (col - 256)] = (__bf16)(v + bias[col - 256]);
      }
    }
  }
}

// ---------------------------------------------------------------- agg
// ONE WAVE PER NODE (avg degree = 8 -> per-node overhead dominates; halve it).
// Block = 4 waves = 4 nodes. Each lane owns 4 dims (dwordx2 = 8B of the 512B
// ft row); 64 lanes cover the full row -> ONE wave-gather per edge (4 lines,
// same line traffic as before but half the VMEM/DS/readlane issue).
// Chunk = 16 edges: lane (es=lane&15, head=lane>>4) computes that edge-head's
// w = exp(leaky(el[s]+er[n]+ee_csr)) -> LDS wl2[wave][es][head] (stride-5 pad,
// conflict-free write; broadcast read). den accumulated per lane's own wv,
// reduced with 4 shfl within the 16-lane head group. Layer-1 head-mean via
// shfl_xor(16|32) -- no LDS round-trip. LAYER 0: +prev, ELU -> bf16 out.
template <int LAYER>
__global__ __launch_bounds__(256) void agg_kernel(const int* __restrict__ off,
                                                  const int* __restrict__ srcc,
                                                  const float* __restrict__ eeoc,
                                                  const float* __restrict__ el,
                                                  const float* __restrict__ er,
                                                  const __bf16* __restrict__ ft,
                                                  const __bf16* prev,
                                                  const float* __restrict__ bias,
                                                  __bf16* outb,
                                                  float* __restrict__ outf) {
  __shared__ f32x2 wl2[4][16][5];  // [wave][edge][head], stride-5 pad
  int t = threadIdx.x;
  int wav = t >> 6, lane = t & 63;
  int es = lane & 15;   // edge slot (setup) / within-head dim-quad (gather)
  int head = lane >> 4;
  int n = blockIdx.x * 4 + wav;
  int beg = off[n], end = off[n + 1];
  float ern = er[n * 4 + head];
  int offb = lane * 8;  // byte offset within 512B ft row

  const char* ftb = (const char*)ft;
  f32x2 acc0 = {0.f, 0.f}, acc1 = {0.f, 0.f};
  float denp = 0.f;

  for (int c = beg; c < end; c += 16) {
    int rem = end - c;
    if (rem > 16) rem = 16;
    int sv = 0;
    float wv = 0.f;
    if (es < rem) {
      sv = srcc[c + es];
      float z = el[sv * 4 + head] + ern + eeoc[(size_t)(c + es) * 4 + head];
      wv = __expf(z > 0.f ? z : 0.2f * z);
    }
    denp += wv;
    wl2[wav][es][head] = (f32x2){wv, wv};
    int kk = 0;
    for (; kk + 8 <= rem; kk += 8) {
      int s0 = __builtin_amdgcn_readlane(sv, kk);
      int s1 = __builtin_amdgcn_readlane(sv, kk + 1);
      int s2 = __builtin_amdgcn_readlane(sv, kk + 2);
      int s3 = __builtin_amdgcn_readlane(sv, kk + 3);
      int s4 = __builtin_amdgcn_readlane(sv, kk + 4);
      int s5 = __builtin_amdgcn_readlane(sv, kk + 5);
      int s6 = __builtin_amdgcn_readlane(sv, kk + 6);
      int s7 = __builtin_amdgcn_readlane(sv, kk + 7);
      uint2 u0 = *(const uint2*)(ftb + (size_t)s0 * 512 + offb);
      uint2 u1 = *(const uint2*)(ftb + (size_t)s1 * 512 + offb);
      uint2 u2 = *(const uint2*)(ftb + (size_t)s2 * 512 + offb);
      uint2 u3 = *(const uint2*)(ftb + (size_t)s3 * 512 + offb);
      uint2 u4 = *(const uint2*)(ftb + (size_t)s4 * 512 + offb);
      uint2 u5 = *(const uint2*)(ftb + (size_t)s5 * 512 + offb);
      uint2 u6 = *(const uint2*)(ftb + (size_t)s6 * 512 + offb);
      uint2 u7 = *(const uint2*)(ftb + (size_t)s7 * 512 + offb);
      f32x2 w0 = wl2[wav][kk][head];
      f32x2 w1 = wl2[wav][kk + 1][head];
      f32x2 w2 = wl2[wav][kk + 2][head];
      f32x2 w3 = wl2[wav][kk + 3][head];
      f32x2 w4 = wl2[wav][kk + 4][head];
      f32x2 w5 = wl2[wav][kk + 5][head];
      f32x2 w6 = wl2[wav][kk + 6][head];
      f32x2 w7 = wl2[wav][kk + 7][head];
      acc0 = __builtin_elementwise_fma(bf2(u0.x), w0, acc0);
      acc1 = __builtin_elementwise_fma(bf2(u0.y), w0, acc1);
      acc0 = __builtin_elementwise_fma(bf2(u1.x), w1, acc0);
      acc1 = __builtin_elementwise_fma(bf2(u1.y), w1, acc1);
      acc0 = __builtin_elementwise_fma(bf2(u2.x), w2, acc0);
      acc1 = __builtin_elementwise_fma(bf2(u2.y), w2, acc1);
      acc0 = __builtin_elementwise_fma(bf2(u3.x), w3, acc0);
      acc1 = __builtin_elementwise_fma(bf2(u3.y), w3, acc1);
      acc0 = __builtin_elementwise_fma(bf2(u4.x), w4, acc0);
      acc1 = __builtin_elementwise_fma(bf2(u4.y), w4, acc1);
      acc0 = __builtin_elementwise_fma(bf2(u5.x), w5, acc0);
      acc1 = __builtin_elementwise_fma(bf2(u5.y), w5, acc1);
      acc0 = __builtin_elementwise_fma(bf2(u6.x), w6, acc0);
      acc1 = __builtin_elementwise_fma(bf2(u6.y), w6, acc1);
      acc0 = __builtin_elementwise_fma(bf2(u7.x), w7, acc0);
      acc1 = __builtin_elementwise_fma(bf2(u7.y), w7, acc1);
    }
    for (; kk + 4 <= rem; kk += 4) {
      int s0 = __builtin_amdgcn_readlane(sv, kk);
      int s1 = __builtin_amdgcn_readlane(sv, kk + 1);
      int s2 = __builtin_amdgcn_readlane(sv, kk + 2);
      int s3 = __builtin_amdgcn_readlane(sv, kk + 3);
      uint2 u0 = *(const uint2*)(ftb + (size_t)s0 * 512 + offb);
      uint2 u1 = *(const uint2*)(ftb + (size_t)s1 * 512 + offb);
      uint2 u2 = *(const uint2*)(ftb + (size_t)s2 * 512 + offb);
      uint2 u3 = *(const uint2*)(ftb + (size_t)s3 * 512 + offb);
      f32x2 w0 = wl2[wav][kk][head];
      f32x2 w1 = wl2[wav][kk + 1][head];
      f32x2 w2 = wl2[wav][kk + 2][head];
      f32x2 w3 = wl2[wav][kk + 3][head];
      acc0 = __builtin_elementwise_fma(bf2(u0.x), w0, acc0);
      acc1 = __builtin_elementwise_fma(bf2(u0.y), w0, acc1);
      acc0 = __builtin_elementwise_fma(bf2(u1.x), w1, acc0);
      acc1 = __builtin_elementwise_fma(bf2(u1.y), w1, acc1);
      acc0 = __builtin_elementwise_fma(bf2(u2.x), w2, acc0);
      acc1 = __builtin_elementwise_fma(bf2(u2.y), w2, acc1);
      acc0 = __builtin_elementwise_fma(bf2(u3.x), w3, acc0);
      acc1 = __builtin_elementwise_fma(bf2(u3.y), w3, acc1);
    }
    for (; kk < rem; ++kk) {
      int s0 = __builtin_amdgcn_readlane(sv, kk);
      uint2 u0 = *(const uint2*)(ftb + (size_t)s0 * 512 + offb);
      f32x2 w0 = wl2[wav][kk][head];
      acc0 = __builtin_elementwise_fma(bf2(u0.x), w0, acc0);
      acc1 = __builtin_elementwise_fma(bf2(u0.y), w0, acc1);
    }
  }
  // den: reduce within the 16-lane head group
#pragma unroll
  for (int m = 1; m < 16; m <<= 1) denp += __shfl_xor(denp, m);

  float r0 = 0.f, r1 = 0.f, r2 = 0.f, r3 = 0.f;
  if (end > beg) {
    float rd = 1.f / denp;
    r0 = acc0.x * rd; r1 = acc0.y * rd;
    r2 = acc1.x * rd; r3 = acc1.y * rd;
  }

  uint2 pu = *(const uint2*)((const char*)prev + (size_t)n * 512 + offb);
  f32x2 p0 = bf2(pu.x), p1 = bf2(pu.y);

  if (LAYER == 0) {
    float v0 = r0 + p0.x, v1 = r1 + p0.y;
    float v2 = r2 + p1.x, v3 = r3 + p1.y;
    v0 = v0 > 0.f ? v0 : (__expf(v0) - 1.0f);  // ELU
    v1 = v1 > 0.f ? v1 : (__expf(v1) - 1.0f);
    v2 = v2 > 0.f ? v2 : (__expf(v2) - 1.0f);
    v3 = v3 > 0.f ? v3 : (__expf(v3) - 1.0f);
    bf16_4 o = {(__bf16)v0, (__bf16)v1, (__bf16)v2, (__bf16)v3};
    *(bf16_4*)((char*)outb + (size_t)n * 512 + offb) = o;
  } else {
    float4 bv = *(const float4*)(bias + lane * 4);
    float s0 = r0 + p0.x + bv.x;
    float s1 = r1 + p0.y + bv.y;
    float s2 = r2 + p1.x + bv.z;
    float s3 = r3 + p1.y + bv.w;
    // mean over heads: dims d, d+64, d+128, d+192 live at lanes l, l+16, l+32, l+48
    s0 += __shfl_xor(s0, 16); s0 += __shfl_xor(s0, 32);
    s1 += __shfl_xor(s1, 16); s1 += __shfl_xor(s1, 32);
    s2 += __shfl_xor(s2, 16); s2 += __shfl_xor(s2, 32);
    s3 += __shfl_xor(s3, 16); s3 += __shfl_xor(s3, 32);
    if (head == 0) {
      float4 s;
      s.x = 0.25f * s0; s.y = 0.25f * s1; s.z = 0.25f * s2; s.w = 0.25f * s3;
      *(float4*)(outf + (size_t)n * 64 + es * 4) = s;
    }
  }
}

// ---------------------------------------------------------------- launch
extern "C" void kernel_launch(void* const* d_in, const int* in_sizes, int n_in,
                              void* d_out, int out_size, void* d_ws, size_t ws_size,
                              hipStream_t stream) {
  const float* features  = (const float*)d_in[0];
  const float* edge_feat = (const float*)d_in[1];
  const int*   src       = (const int*)d_in[2];
  const int*   dst       = (const int*)d_in[3];
  const float* W0    = (const float*)d_in[4];
  const float* We0   = (const float*)d_in[5];
  const float* al0   = (const float*)d_in[6];
  const float* ar0   = (const float*)d_in[7];
  const float* ae0   = (const float*)d_in[8];
  const float* b0    = (const float*)d_in[9];
  const float* Wres0 = (const float*)d_in[10];
  const float* W1    = (const float*)d_in[11];
  const float* We1   = (const float*)d_in[12];
  const float* al1   = (const float*)d_in[13];
  const float* ar1   = (const float*)d_in[14];
  const float* ae1   = (const float*)d_in[15];
  const float* b1    = (const float*)d_in[16];
  float* out = (float*)d_out;

  char* ws = (char*)d_ws;
  size_t o = 0;
  auto alloc = [&](size_t bytes) {
    void* p = ws + o;
    o = (o + bytes + 255) & ~(size_t)255;
    return p;
  };
  int*    cnt      = (int*)alloc((size_t)NN * 4);
  int*    scanbuf  = (int*)alloc((size_t)NN * 4);
  int*    blocksum = (int*)alloc(256 * 4);
  int*    off      = (int*)alloc((size_t)(NN + 1) * 4);
  int*    cur      = (int*)alloc((size_t)NN * 4);
  int*    srcc     = (int*)alloc((size_t)EE * 4);
  float*  eeo0c    = (float*)alloc((size_t)EE * 4 * 4);
  float*  eeo1c    = (float*)alloc((size_t)EE * 4 * 4);
  float*  el       = (float*)alloc((size_t)NN * 4 * 4);
  float*  er       = (float*)alloc((size_t)NN * 4 * 4);
  float*  Ve0      = (float*)alloc(256 * 4);
  float*  Ve1      = (float*)alloc(256 * 4);
  __bf16* Bt0      = (__bf16*)alloc((size_t)512 * 64 * 2);
  __bf16* Bt1      = (__bf16*)alloc((size_t)256 * 256 * 2);
  __bf16* fbf      = (__bf16*)alloc((size_t)NN * 64 * 2);
  __bf16* ft       = (__bf16*)alloc((size_t)NN * 256 * 2);
  __bf16* base     = (__bf16*)alloc((size_t)NN * 256 * 2);  // h1 aliases base
  __bf16* h1       = base;

  const int EB = (EE + 255) / 256;   // 1563
  const int MG = (NN + 63) / 64;     // 782

  hipMemsetAsync(cnt, 0, (size_t)NN * 4, stream);
  prep_kernel<<<1949 + EB, 256, 0, stream>>>(features, fbf, W0, Wres0, Bt0, W1, Bt1,
                                             We0, ae0, Ve0, We1, ae1, Ve1, dst, cnt);
  scan1_kernel<<<NB, 256, 0, stream>>>(cnt, scanbuf, blocksum);
  scan23_kernel<<<NB, 256, 0, stream>>>(scanbuf, cnt, blocksum, off, cur);
  filleek_kernel<<<EE / 64, 256, 0, stream>>>(src, dst, cur, srcc, edge_feat,
                                              Ve0, Ve1, eeo0c, eeo1c);

  // ---- layer 0
  gemm_kernel<<<dim3(MG, 8), 256, 0, stream>>>(fbf, Bt0, ft, base, b0, al0, ar0, el, er, NN, 64);
  agg_kernel<0><<<NN / 4, 256, 0, stream>>>(off, srcc, eeo0c, el, er, ft, base, nullptr, h1, nullptr);

  // ---- layer 1
  gemm_kernel<<<dim3(MG, 4), 256, 0, stream>>>(h1, Bt1, ft, nullptr, nullptr, al1, ar1, el, er, NN, 256);
  agg_kernel<1><<<NN / 4, 256, 0, stream>>>(off, srcc, eeo1c, el, er, ft, h1, b1, nullptr, out);
}